// Round 3
// 3564.469 us; speedup vs baseline: 1.9398x; 1.9398x over previous
//
#include <hip/hip_runtime.h>
#include <math.h>

#define D 768
#define NH 12
#define DH 64
#define FF 3072
#define NL 12
#define QL 512
#define CL 2048
#define NB 2
#define M_TOT 5120   // 2*512 + 2*2048 tokens, q rows first
#define NTB 80       // M_TOT/64 token blocks
#define CHUNKSZ 256
#define WINSZ 256
#define QSTR 2304    // fused QKV row stride
#define KP 72        // P-buffer row stride (shorts), 16B-multiple

typedef short bf16x8 __attribute__((ext_vector_type(8)));
typedef short s16x4 __attribute__((ext_vector_type(4)));
typedef float f32x4 __attribute__((ext_vector_type(4)));

__device__ __forceinline__ short f2bf(float x) {
    union { float f; unsigned u; } v; v.f = x;
    unsigned r = v.u + 0x7fffu + ((v.u >> 16) & 1u);   // round-to-nearest-even
    return (short)(r >> 16);
}

#define GLD16(gp, lp) __builtin_amdgcn_global_load_lds( \
    (const __attribute__((address_space(1))) unsigned int*)(gp), \
    (__attribute__((address_space(3))) unsigned int*)(lp), 16, 0, 0)

// ---------------- block-wide reductions (256 threads) ----------------
__device__ __forceinline__ float block_reduce_sum(float v, float* red, int t) {
    red[t] = v; __syncthreads();
    #pragma unroll
    for (int o = 128; o > 0; o >>= 1) {
        if (t < o) red[t] += red[t + o];
        __syncthreads();
    }
    float r = red[0];
    __syncthreads();
    return r;
}

__device__ __forceinline__ float block_reduce_max(float v, float* red, int t) {
    red[t] = v; __syncthreads();
    #pragma unroll
    for (int o = 128; o > 0; o >>= 1) {
        if (t < o) red[t] = fmaxf(red[t], red[t + o]);
        __syncthreads();
    }
    float r = red[0];
    __syncthreads();
    return r;
}

// ---------------- MFMA GEMM: C = op(A[M,K] @ Bt[N,K]^T + bias) ----------------
// A, Bt bf16 row-major; 128x128 tile, BK=32, 4 waves each 64x64 (4x4 frags of 16x16x32)
// OP: 0 none, 2 exact gelu. WF32: fp32 to Cf (stride ldc). WBF16: bf16 to Cb (stride N).
// WVT: additionally write V columns (n >= 2*D) transposed per head into
//      Vtb[head][tokblk][dh][tok&63] (bf16, 64x64 blocks).
template<int OP, int WF32, int WBF16, int WVT>
__global__ __launch_bounds__(256)
void mfma_gemm(const short* __restrict__ A, const short* __restrict__ Bt,
               const float* __restrict__ bias, float* __restrict__ Cf,
               short* __restrict__ Cb, short* __restrict__ Vtb,
               int M, int N, int K, int ldc,
               long aZ, long btZ, long cZ)
{
    __shared__ short As[128 * 32];
    __shared__ short Bs[128 * 32];
    const int tid = threadIdx.x;
    const int wave = tid >> 6, lane = tid & 63;
    const int m0 = blockIdx.x * 128, n0 = blockIdx.y * 128;
    const int wm = (wave >> 1) * 64, wn = (wave & 1) * 64;
    A  += (size_t)blockIdx.z * aZ;
    Bt += (size_t)blockIdx.z * btZ;

    const int srow = tid >> 2;
    const int skg  = (tid & 3) << 3;
    const short* gA = A  + (size_t)(m0 + srow) * K + skg;
    const short* gB = Bt + (size_t)(n0 + srow) * K + skg;

    f32x4 acc[4][4] = {};
    const int lrow = lane & 15;
    const int lk   = (lane >> 4) << 3;

    for (int k0 = 0; k0 < K; k0 += 32) {
        if (k0) __syncthreads();
        GLD16(gA + k0,                 As + tid * 8);
        GLD16(gA + k0 + (size_t)64*K,  As + (tid + 256) * 8);
        GLD16(gB + k0,                 Bs + tid * 8);
        GLD16(gB + k0 + (size_t)64*K,  Bs + (tid + 256) * 8);
        __syncthreads();
        bf16x8 af[4], bfv[4];
        #pragma unroll
        for (int i = 0; i < 4; i++) af[i]  = *(const bf16x8*)(As + (wm + i*16 + lrow)*32 + lk);
        #pragma unroll
        for (int j = 0; j < 4; j++) bfv[j] = *(const bf16x8*)(Bs + (wn + j*16 + lrow)*32 + lk);
        #pragma unroll
        for (int i = 0; i < 4; i++)
            #pragma unroll
            for (int j = 0; j < 4; j++)
                acc[i][j] = __builtin_amdgcn_mfma_f32_16x16x32_bf16(af[i], bfv[j], acc[i][j], 0, 0, 0);
    }

    const int cn = lane & 15;
    const int rq = (lane >> 4) << 2;
    #pragma unroll
    for (int j = 0; j < 4; j++) {
        int n = n0 + wn + j * 16 + cn;
        float bv = bias ? bias[n] : 0.f;
        #pragma unroll
        for (int i = 0; i < 4; i++) {
            int mb = m0 + wm + i * 16 + rq;
            float v4[4];
            #pragma unroll
            for (int r2 = 0; r2 < 4; r2++) {
                float v = acc[i][j][r2] + bv;
                if (OP == 2) v = 0.5f * v * (1.0f + erff(v * 0.70710678118654752f));
                v4[r2] = v;
                if (WF32)  Cf[(size_t)blockIdx.z * cZ + (size_t)(mb + r2) * ldc + n] = v;
                if (WBF16) Cb[(size_t)(mb + r2) * N + n] = f2bf(v);
            }
            if (WVT && n >= 2 * D) {
                int head = (n - 2 * D) >> 6, dh = (n - 2 * D) & 63;
                s16x4 s4 = { f2bf(v4[0]), f2bf(v4[1]), f2bf(v4[2]), f2bf(v4[3]) };
                *(s16x4*)(Vtb + (((size_t)(head * NTB + (mb >> 6)) << 12) | (dh << 6) | (mb & 63))) = s4;
            }
        }
    }
}

// ---------------- weight transpose + bf16 convert ----------------
__global__ __launch_bounds__(256)
void conv_qkvo(const float* __restrict__ Wq, const float* __restrict__ Wk,
               const float* __restrict__ Wv, const float* __restrict__ Wo,
               short* __restrict__ WtQKV, short* __restrict__ WtO)
{
    __shared__ float tl[32][33];
    int z = blockIdx.z;
    const float* src = (z == 0) ? Wq : (z == 1) ? Wk : (z == 2) ? Wv : Wo;
    float scale = (z == 0) ? 0.125f : 1.0f;
    short* dst = (z < 3) ? (WtQKV + (size_t)z * D * D) : WtO;
    int r0 = blockIdx.y * 32, c0 = blockIdx.x * 32;
    int tx = threadIdx.x & 31, ty = threadIdx.x >> 5;
    #pragma unroll
    for (int i = 0; i < 4; i++)
        tl[ty + 8*i][tx] = src[(size_t)(r0 + ty + 8*i) * D + c0 + tx] * scale;
    __syncthreads();
    #pragma unroll
    for (int i = 0; i < 4; i++)
        dst[(size_t)(c0 + ty + 8*i) * D + r0 + tx] = f2bf(tl[tx][ty + 8*i]);
}

__global__ __launch_bounds__(256)
void transpose_bf(const float* __restrict__ in, short* __restrict__ out, int R, int C)
{
    __shared__ float tl[32][33];
    int r0 = blockIdx.y * 32, c0 = blockIdx.x * 32;
    int tx = threadIdx.x & 31, ty = threadIdx.x >> 5;
    #pragma unroll
    for (int i = 0; i < 4; i++)
        tl[ty + 8*i][tx] = in[(size_t)(r0 + ty + 8*i) * C + c0 + tx];
    __syncthreads();
    #pragma unroll
    for (int i = 0; i < 4; i++)
        out[(size_t)(c0 + ty + 8*i) * R + r0 + tx] = f2bf(tl[tx][ty + 8*i]);
}

__global__ __launch_bounds__(256)
void bias_cat(const float* __restrict__ bq, const float* __restrict__ bk,
              const float* __restrict__ bv, float* __restrict__ ob)
{
    int i = blockIdx.x * 256 + threadIdx.x;
    if (i >= QSTR) return;
    if (i < D) ob[i] = bq[i] * 0.125f;
    else if (i < 2 * D) ob[i] = bk[i - D];
    else ob[i] = bv[i - 2 * D];
}

// ---------------- embedding + LN (writes fp32 h and bf16 copy) ----------------
__global__ __launch_bounds__(256)
void embed_kernel(const int* __restrict__ q_ids, const int* __restrict__ c_ids,
                  const float* __restrict__ we, const float* __restrict__ pe,
                  const float* __restrict__ te,
                  const float* __restrict__ g, const float* __restrict__ bp,
                  float* __restrict__ hbuf, short* __restrict__ hb)
{
    __shared__ float red[256];
    int row = blockIdx.x;
    int id, s;
    if (row < NB * QL) { int b = row / QL; s = row % QL; id = q_ids[b * QL + s]; }
    else { int r = row - NB * QL; int b = r / CL; s = r % CL; id = c_ids[b * CL + s]; }
    int t = threadIdx.x;
    float x[3];
    float sum = 0.f;
    #pragma unroll
    for (int i = 0; i < 3; i++) {
        int d = t + i * 256;
        x[i] = we[(size_t)id * D + d] + pe[(size_t)s * D + d] + te[d];
        sum += x[i];
    }
    float mean = block_reduce_sum(sum, red, t) * (1.0f / D);
    float vs = 0.f;
    #pragma unroll
    for (int i = 0; i < 3; i++) { float dv = x[i] - mean; vs += dv * dv; }
    float var = block_reduce_sum(vs, red, t) * (1.0f / D);
    float rstd = rsqrtf(var + 1e-12f);
    #pragma unroll
    for (int i = 0; i < 3; i++) {
        int d = t + i * 256;
        float y = (x[i] - mean) * rstd * g[d] + bp[d];
        hbuf[(size_t)row * D + d] = y;
        hb[(size_t)row * D + d] = f2bf(y);
    }
}

// ---------------- residual add + LN (in place, writes fp32 + bf16) ----------------
__global__ __launch_bounds__(256)
void add_ln_kernel(float* __restrict__ hbuf, const float* __restrict__ delta,
                   const float* __restrict__ g, const float* __restrict__ bp,
                   short* __restrict__ hb)
{
    __shared__ float red[256];
    int row = blockIdx.x;
    int t = threadIdx.x;
    float x[3];
    float sum = 0.f;
    #pragma unroll
    for (int i = 0; i < 3; i++) {
        int d = t + i * 256;
        x[i] = hbuf[(size_t)row * D + d] + delta[(size_t)row * D + d];
        sum += x[i];
    }
    float mean = block_reduce_sum(sum, red, t) * (1.0f / D);
    float vs = 0.f;
    #pragma unroll
    for (int i = 0; i < 3; i++) { float dv = x[i] - mean; vs += dv * dv; }
    float var = block_reduce_sum(vs, red, t) * (1.0f / D);
    float rstd = rsqrtf(var + 1e-12f);
    #pragma unroll
    for (int i = 0; i < 3; i++) {
        int d = t + i * 256;
        float y = (x[i] - mean) * rstd * g[d] + bp[d];
        hbuf[(size_t)row * D + d] = y;
        hb[(size_t)row * D + d] = f2bf(y);
    }
}

// ---------------- MFMA sliding-window attention (16x16x32 only) ----------------
// grid (20, 12): 20 chunks of 256 q-rows x 12 heads; 256 threads = 4 waves x 64 q-rows.
// All fragment layouts are the harness-proven 16x16x32 set (identical to mfma_gemm):
//   A: row=lane&15, k=(lane>>4)*8+j ; B: col=lane&15, same k ;
//   C: col=lane&15, row=(lane>>4)*4+reg.
// K and V^T are staged FRAGMENT-MAJOR in LDS: slot (fb, lane) holds exactly the 16B
// that lane reads later as its fragment -> lane-linear ds_read_b128, conflict-free,
// no swizzle algebra. P[q][key] goes through a per-wave LDS buffer (pad KP=72).
__global__ __launch_bounds__(256)
void attn_mfma(const short* __restrict__ QKV, const short* __restrict__ Vt,
               const int* __restrict__ mq, const int* __restrict__ mc,
               short* __restrict__ Ao)
{
    __shared__ short Kf[8 * 64 * 8];     // [fb = kt*2+kb][lane][8]
    __shared__ short Vf[8 * 64 * 8];     // [fb = dt*2+kb][lane][8]
    __shared__ short Ps[4][64 * KP];     // per-wave P[q][key]

    const int cg = blockIdx.x, head = blockIdx.y;
    int base, n, nc;
    const int* mask;
    if (cg < 4) { int b = cg >> 1; n = cg & 1; nc = QL / CHUNKSZ; base = b * QL; mask = mq + b * QL; }
    else { int t2 = cg - 4; int b = t2 >> 3; n = t2 & 7; nc = CL / CHUNKSZ; base = NB * QL + b * CL; mask = mc + b * CL; }

    const int tid = threadIdx.x;
    const int wave = tid >> 6, lane = tid & 63;
    const int l15 = lane & 15, g4 = lane >> 4;
    const int wq0 = wave * 64;
    const int qrow0 = base + n * CHUNKSZ + wq0;
    const int qpos0 = n * CHUNKSZ + wq0;

    short* myP = &Ps[wave][0];

    // Q fragments (B-operand): qf[qt][kb][j] = Q[qrow0+qt*16+l15][kb*32 + g4*8 + j]
    bf16x8 qf[4][2];
    #pragma unroll
    for (int qt = 0; qt < 4; qt++)
        #pragma unroll
        for (int kb = 0; kb < 2; kb++)
            qf[qt][kb] = *(const bf16x8*)(QKV + (size_t)(qrow0 + qt*16 + l15) * QSTR
                                          + head * DH + kb * 32 + g4 * 8);

    f32x4 o[4][4] = {};                         // [qt][dt]; C: col=l15=d, row=g4*4+reg=q
    float mrow[4] = {-1e4f, -1e4f, -1e4f, -1e4f};
    float lrow[4] = {0.f, 0.f, 0.f, 0.f};

    const int c_lo = (n - 1 < 0) ? 0 : n - 1;
    const int c_hi = (n + 1 > nc - 1) ? nc - 1 : n + 1;
    const int ngr = (c_hi - c_lo + 1) * 4;

    for (int g = 0; g < ngr; ++g) {
        const int cidx = c_lo + (g >> 2);
        const int t4 = g & 3;
        const int tok0 = base + cidx * CHUNKSZ + t4 * 64;
        const int kg0 = cidx * CHUNKSZ + t4 * 64;

        __syncthreads();
        // K fragment-major staging: slot p -> fb=p>>6 (kt=fb>>1, kb=fb&1), li=p&63
        #pragma unroll
        for (int i = 0; i < 2; i++) {
            int p = tid + i * 256;
            int fb = p >> 6, li = p & 63;
            int kt = fb >> 1, kb = fb & 1;
            GLD16(QKV + (size_t)(tok0 + kt*16 + (li & 15)) * QSTR + D + head*DH + kb*32 + (li >> 4)*8,
                  Kf + p * 8);
        }
        // V^T fragment-major staging from Vtb block: fb=dt*2+kb
        const short* vtb = Vt + ((size_t)(head * NTB + (tok0 >> 6)) << 12);
        #pragma unroll
        for (int i = 0; i < 2; i++) {
            int p = tid + i * 256;
            int fb = p >> 6, li = p & 63;
            int dt = fb >> 1, kb = fb & 1;
            GLD16(vtb + (dt*16 + (li & 15)) * 64 + kb*32 + (li >> 4)*8,
                  Vf + p * 8);
        }
        int mv = mask[kg0 + lane];
        unsigned long long mb = __ballot(mv > 0);
        bool maskall = (mb == 0xFFFFFFFFFFFFFFFFull);
        __syncthreads();

        // resident fragments for this group
        bf16x8 kf[4][2], vfr[4][2];
        #pragma unroll
        for (int kt = 0; kt < 4; kt++)
            #pragma unroll
            for (int kb = 0; kb < 2; kb++)
                kf[kt][kb] = *(const bf16x8*)(Kf + ((kt*2 + kb) * 64 + lane) * 8);
        #pragma unroll
        for (int dt = 0; dt < 4; dt++)
            #pragma unroll
            for (int kb = 0; kb < 2; kb++)
                vfr[dt][kb] = *(const bf16x8*)(Vf + ((dt*2 + kb) * 64 + lane) * 8);

        const bool fastwin = maskall &&
            (kg0 - (qpos0 + 63) >= -WINSZ) && (kg0 + 63 - qpos0 <= WINSZ);

        #pragma unroll
        for (int qt = 0; qt < 4; qt++) {
            // ---- S^T tiles: rows = keys (kt*16 + g4*4 + reg), cols = q (qt*16 + l15) ----
            f32x4 sc[4] = {};
            #pragma unroll
            for (int kt = 0; kt < 4; kt++) {
                sc[kt] = __builtin_amdgcn_mfma_f32_16x16x32_bf16(kf[kt][0], qf[qt][0], sc[kt], 0, 0, 0);
                sc[kt] = __builtin_amdgcn_mfma_f32_16x16x32_bf16(kf[kt][1], qf[qt][1], sc[kt], 0, 0, 0);
            }
            if (!fastwin) {
                int qp = qpos0 + qt * 16 + l15;
                #pragma unroll
                for (int kt = 0; kt < 4; kt++)
                    #pragma unroll
                    for (int r = 0; r < 4; r++) {
                        int kk = kt * 16 + g4 * 4 + r;
                        int rel = kg0 + kk - qp;
                        bool ok = ((unsigned)(rel + WINSZ) <= 2u * WINSZ) && ((mb >> kk) & 1ull);
                        if (!ok) sc[kt][r] = -1e30f;
                    }
            }
            // ---- online softmax over the 64 keys (per q = l15 column) ----
            float t = fmaxf(fmaxf(sc[0][0], sc[0][1]), fmaxf(sc[0][2], sc[0][3]));
            t = fmaxf(t, fmaxf(fmaxf(sc[1][0], sc[1][1]), fmaxf(sc[1][2], sc[1][3])));
            t = fmaxf(t, fmaxf(fmaxf(sc[2][0], sc[2][1]), fmaxf(sc[2][2], sc[2][3])));
            t = fmaxf(t, fmaxf(fmaxf(sc[3][0], sc[3][1]), fmaxf(sc[3][2], sc[3][3])));
            t = fmaxf(t, __shfl_xor(t, 16));
            t = fmaxf(t, __shfl_xor(t, 32));
            float mo = mrow[qt];
            float mn = fmaxf(mo, t);
            if (__any(mn > mo)) {
                float al = __expf(mo - mn);
                mrow[qt] = mn;
                lrow[qt] *= al;
                float av0 = __shfl(al, g4 * 4 + 0);
                float av1 = __shfl(al, g4 * 4 + 1);
                float av2 = __shfl(al, g4 * 4 + 2);
                float av3 = __shfl(al, g4 * 4 + 3);
                #pragma unroll
                for (int dt = 0; dt < 4; dt++) {
                    o[qt][dt][0] *= av0; o[qt][dt][1] *= av1;
                    o[qt][dt][2] *= av2; o[qt][dt][3] *= av3;
                }
            }
            float ssum = 0.f;
            short* prow = myP + (qt * 16 + l15) * KP;
            #pragma unroll
            for (int kt = 0; kt < 4; kt++) {
                float p0 = __expf(sc[kt][0] - mrow[qt]);
                float p1 = __expf(sc[kt][1] - mrow[qt]);
                float p2 = __expf(sc[kt][2] - mrow[qt]);
                float p3 = __expf(sc[kt][3] - mrow[qt]);
                ssum += (p0 + p1) + (p2 + p3);
                s16x4 w = { f2bf(p0), f2bf(p1), f2bf(p2), f2bf(p3) };
                *(s16x4*)(prow + kt * 16 + g4 * 4) = w;   // P[q][kt*16+g4*4 ..+3]
            }
            ssum += __shfl_xor(ssum, 16);
            ssum += __shfl_xor(ssum, 32);
            lrow[qt] += ssum;

            // wave-private P write -> read (in-order DS pipe; explicit drain for safety)
            asm volatile("s_waitcnt lgkmcnt(0)" ::: "memory");
            bf16x8 pa0 = *(const bf16x8*)(prow + g4 * 8);        // keys  0..31 slice
            bf16x8 pa1 = *(const bf16x8*)(prow + 32 + g4 * 8);   // keys 32..63 slice
            #pragma unroll
            for (int dt = 0; dt < 4; dt++) {
                o[qt][dt] = __builtin_amdgcn_mfma_f32_16x16x32_bf16(pa0, vfr[dt][0], o[qt][dt], 0, 0, 0);
                o[qt][dt] = __builtin_amdgcn_mfma_f32_16x16x32_bf16(pa1, vfr[dt][1], o[qt][dt], 0, 0, 0);
            }
        }
    }

    // ---- epilogue: normalize + store bf16 ----
    #pragma unroll
    for (int qt = 0; qt < 4; qt++) {
        float iv[4];
        #pragma unroll
        for (int r = 0; r < 4; r++) {
            float lv = __shfl(lrow[qt], g4 * 4 + r);
            iv[r] = (lv > 0.f) ? 1.f / lv : 0.f;
        }
        #pragma unroll
        for (int dt = 0; dt < 4; dt++) {
            short* op = Ao + (size_t)(qrow0 + qt * 16 + g4 * 4) * D + head * DH + dt * 16 + l15;
            #pragma unroll
            for (int r = 0; r < 4; r++)
                op[(size_t)r * D] = f2bf(o[qt][dt][r] * iv[r]);
        }
    }
}

// ---------------- interaction softmax over q axis (in place) ----------------
__global__ __launch_bounds__(256)
void inter_softmax(float* __restrict__ scores)
{
    __shared__ float red[256];
    int t = threadIdx.x;
    float* rowp = scores + ((size_t)blockIdx.y * CL + blockIdx.x) * QL;
    float s0 = rowp[t], s1 = rowp[t + 256];
    float mx = block_reduce_max(fmaxf(s0, s1), red, t);
    float e0 = __expf(s0 - mx), e1 = __expf(s1 - mx);
    float ssum = block_reduce_sum(e0 + e1, red, t);
    float inv = 1.f / ssum;
    rowp[t] = e0 * inv;
    rowp[t + 256] = e1 * inv;
}

// ---------------- column max over c axis, 2-stage ----------------
__global__ __launch_bounds__(256)
void colmax_part(const float* __restrict__ probs, float* __restrict__ part)
{
    int j = blockIdx.x * 256 + threadIdx.x;   // 0..1023 -> (b, q)
    int b = j >> 9, q = j & 511;
    const float* p = probs + (size_t)b * CL * QL + q;
    int i0 = blockIdx.y * 128;
    float mx = -1e30f;
    for (int i = 0; i < 128; i++) mx = fmaxf(mx, p[(size_t)(i0 + i) * QL]);
    part[blockIdx.y * 1024 + j] = mx;
}

__global__ __launch_bounds__(256)
void colmax_fin(const float* __restrict__ part, float* __restrict__ tail)
{
    int j = blockIdx.x * 256 + threadIdx.x;
    float mx = -1e30f;
    #pragma unroll
    for (int y = 0; y < 16; y++) mx = fmaxf(mx, part[y * 1024 + j]);
    tail[j] = mx;
}

// ---------------- final fc ----------------
__global__ __launch_bounds__(256)
void fc_kernel(const float* __restrict__ mout, const float* __restrict__ fcw,
               const float* __restrict__ fcb, float* __restrict__ out)
{
    __shared__ float red[256];
    int t = threadIdx.x;
    for (int b = 0; b < NB; b++) {
        for (int o = 0; o < 4; o++) {
            float s = 0.f;
            for (int j = t; j < QL; j += 256) s += mout[b * QL + j] * fcw[j * 4 + o];
            float tot = block_reduce_sum(s, red, t);
            if (t == 0) out[b * 4 + o] = tot + fcb[o];
            __syncthreads();
        }
    }
}

extern "C" void kernel_launch(void* const* d_in, const int* in_sizes, int n_in,
                              void* d_out, int out_size, void* d_ws, size_t ws_size,
                              hipStream_t stream)
{
    (void)in_sizes; (void)n_in; (void)out_size; (void)ws_size;
    const int*   q_ids  = (const int*)d_in[0];
    const int*   c_ids  = (const int*)d_in[1];
    const int*   q_mask = (const int*)d_in[2];
    const int*   c_mask = (const int*)d_in[3];
    const float* we  = (const float*)d_in[4];
    const float* pe  = (const float*)d_in[5];
    const float* te  = (const float*)d_in[6];
    const float* eg  = (const float*)d_in[7];
    const float* ebp = (const float*)d_in[8];
    const float* Wq  = (const float*)d_in[9];
    const float* bq  = (const float*)d_in[10];
    const float* Wk  = (const float*)d_in[11];
    const float* bk  = (const float*)d_in[12];
    const float* Wv  = (const float*)d_in[13];
    const float* bv  = (const float*)d_in[14];
    const float* Wo  = (const float*)d_in[15];
    const float* bo  = (const float*)d_in[16];
    const float* g1  = (const float*)d_in[17];
    const float* be1 = (const float*)d_in[18];
    const float* W1  = (const float*)d_in[19];
    const float* bf1 = (const float*)d_in[20];
    const float* W2  = (const float*)d_in[21];
    const float* bf2 = (const float*)d_in[22];
    const float* g2  = (const float*)d_in[23];
    const float* be2 = (const float*)d_in[24];
    const float* fcw = (const float*)d_in[25];
    const float* fcb = (const float*)d_in[26];

    const size_t SZ    = (size_t)M_TOT * D;       //  3,932,160 f
    const size_t QKVSZ = (size_t)M_TOT * QSTR;    // 11,796,480 f
    const size_t WTEL  = (size_t)QSTR * D + (size_t)D * D + 2 * (size_t)D * FF; // 7,077,888 el

    float* ws      = (float*)d_ws;
    float* h       = ws;                                   // fp32 [M_TOT, D]
    short* h_bf    = (short*)(h + SZ);                     // bf16 [M_TOT, D]
    float* QKVbuf  = h + SZ + SZ / 2;                      // region [M_TOT, 2304] fp32-sized
    short* attnout = (short*)(QKVbuf + QKVSZ);             // bf16 [M_TOT, D]
    short* Wt      = (short*)(QKVbuf + QKVSZ + SZ / 2);    // per-layer weights bf16
    float* misc    = (float*)(Wt + WTEL);
    float* qkvbias = misc;                                 // [2304]
    float* part    = misc + QSTR;                          // [16*1024]
    float* tail    = part + 16384;                         // [1024]

    short* WtQKV   = Wt;                                   // [2304, 768]
    short* WtO     = Wt + (size_t)QSTR * D;                // [768, 768]
    short* Wt1     = WtO + (size_t)D * D;                  // [3072, 768]
    short* Wt2     = Wt1 + (size_t)D * FF;                 // [768, 3072]

    short* qkv_bf  = (short*)QKVbuf;                       // bf16 [M_TOT, 2304] (aliases QKV region)
    short* ffn1_bf = (short*)QKVbuf;                       // bf16 [M_TOT, FF] (aliases QKV)
    float* deltaF  = QKVbuf + SZ * 2;                      // fp32 [M_TOT, D] (aliases QKV tail)
    float* scores  = QKVbuf;                               // fp32 [NB, CL, QL] (aliases QKV)
    // Vtb aliases deltaF: live only between QKV-GEMM (writer) and attn (reader);
    // deltaF is next written by the O-proj GEMM, which runs after attn.
    short* Vtb     = (short*)deltaF;                       // bf16 [NH, NTB, 64, 64]

    embed_kernel<<<M_TOT, 256, 0, stream>>>(q_ids, c_ids, we, pe, te, eg, ebp, h, h_bf);

    for (int l = 0; l < NL; ++l) {
        const size_t oDD = (size_t)l * D * D;
        const size_t oDF = (size_t)l * D * FF;
        conv_qkvo<<<dim3(24, 24, 4), 256, 0, stream>>>(Wq + oDD, Wk + oDD, Wv + oDD, Wo + oDD, WtQKV, WtO);
        transpose_bf<<<dim3(FF/32, D/32), 256, 0, stream>>>(W1 + oDF, Wt1, D, FF);
        transpose_bf<<<dim3(D/32, FF/32), 256, 0, stream>>>(W2 + oDF, Wt2, FF, D);
        bias_cat<<<9, 256, 0, stream>>>(bq + (size_t)l * D, bk + (size_t)l * D, bv + (size_t)l * D, qkvbias);

        // fused QKV: [M_TOT, 768] @ [2304, 768]^T -> bf16 [M_TOT, 2304] + V^T blocks
        mfma_gemm<0,0,1,1><<<dim3(M_TOT/128, QSTR/128), 256, 0, stream>>>(
            h_bf, WtQKV, qkvbias, nullptr, qkv_bf, Vtb, M_TOT, QSTR, D, QSTR, 0, 0, 0);
        attn_mfma<<<dim3(20, NH), 256, 0, stream>>>(qkv_bf, Vtb, q_mask, c_mask, attnout);
        // O proj -> fp32 delta
        mfma_gemm<0,1,0,0><<<dim3(M_TOT/128, D/128), 256, 0, stream>>>(
            attnout, WtO, bo + (size_t)l * D, deltaF, nullptr, nullptr, M_TOT, D, D, D, 0, 0, 0);
        add_ln_kernel<<<M_TOT, 256, 0, stream>>>(h, deltaF, g1 + (size_t)l * D, be1 + (size_t)l * D, h_bf);
        // FFN1 + gelu -> bf16
        mfma_gemm<2,0,1,0><<<dim3(M_TOT/128, FF/128), 256, 0, stream>>>(
            h_bf, Wt1, bf1 + (size_t)l * FF, nullptr, ffn1_bf, nullptr, M_TOT, FF, D, FF, 0, 0, 0);
        // FFN2 -> fp32 delta
        mfma_gemm<0,1,0,0><<<dim3(M_TOT/128, D/128), 256, 0, stream>>>(
            ffn1_bf, Wt2, bf2 + (size_t)l * D, deltaF, nullptr, nullptr, M_TOT, D, FF, D, 0, 0, 0);
        add_ln_kernel<<<M_TOT, 256, 0, stream>>>(h, deltaF, g2 + (size_t)l * D, be2 + (size_t)l * D, h_bf);
    }

    // interaction: scores[b] = c_h[b] @ q_h[b]^T   (A = c rows, Bt = q rows, both bf16)
    mfma_gemm<0,1,0,0><<<dim3(CL/128, QL/128, NB), 256, 0, stream>>>(
        h_bf + (size_t)NB * QL * D, h_bf, nullptr, scores, nullptr, nullptr,
        CL, QL, D, QL, (long)CL * D, (long)QL * D, (long)CL * QL);
    inter_softmax<<<dim3(CL, NB), 256, 0, stream>>>(scores);
    colmax_part<<<dim3(4, 16), 256, 0, stream>>>(scores, part);
    colmax_fin<<<4, 256, 0, stream>>>(part, tail);
    fc_kernel<<<1, 256, 0, stream>>>(tail, fcw, fcb, (float*)d_out);
}